// Round 1
// baseline (505.858 us; speedup 1.0000x reference)
//
#include <hip/hip_runtime.h>
#include <cmath>

// IPOT solver: n=32768 rows, K=512 cols, 20 iterations.
// Only sigma[512] is true carried state; one matrix pass per iteration.
// K_mat = exp(2C) is materialized into d_out (exact size match) and the
// final pass overwrites it in place with Q*n.

namespace {
constexpr int ROWS = 32768;
constexpr int COLS = 512;
constexpr float INV_BETA = 2.0f;          // 1/0.5
constexpr float EPS = 1e-12f;
constexpr float A_M = 1.0f / 32768.0f;    // row marginal a
constexpr float B_M = 1.0f / 512.0f;      // col marginal b
constexpr int PASS_BLOCKS = 512;          // 2 blocks/CU on 256 CUs
constexpr int INIT_BLOCKS = 2048;
}

// ---- init: K_mat = exp(2*C) into d_out; sigma0 = 1/K; tsum = 0 ----
__global__ __launch_bounds__(256) void ipot_init_kernel(
    const float* __restrict__ C, float* __restrict__ Kmat,
    float* __restrict__ ws /* [0..511]=sigma, [512..1023]=tsum */) {
  const size_t stride = (size_t)gridDim.x * blockDim.x;
  const size_t tid = (size_t)blockIdx.x * blockDim.x + threadIdx.x;
  const float4* c4 = (const float4*)C;
  float4* k4 = (float4*)Kmat;
  const size_t n4 = (size_t)ROWS * COLS / 4;
  for (size_t idx = tid; idx < n4; idx += stride) {
    float4 c = c4[idx];
    float4 k;
    k.x = expf(c.x * INV_BETA);
    k.y = expf(c.y * INV_BETA);
    k.z = expf(c.z * INV_BETA);
    k.w = expf(c.w * INV_BETA);
    k4[idx] = k;
  }
  if (tid < COLS) {
    ws[tid] = B_M;            // sigma0 = 1/K
    ws[COLS + tid] = 0.0f;    // tsum = 0
  }
}

// ---- main pass ----
// Each wave (64 lanes) owns whole rows: lane l holds cols [4l..4l+3] and
// [256+4l..256+4l+3] as two float4 (fully coalesced 2KB/row per wave).
// r_i via wave shfl reduction; column partials accumulate in 8 registers
// per lane (lane->column map is fixed), combined through LDS at the end,
// then one atomicAdd per column per block (512 atomics/block).
template <bool WRITE_OUT>
__global__ __launch_bounds__(256) void ipot_pass_kernel(
    const float* Kmat, float* out, float* __restrict__ ws) {
  __shared__ float lds[4][COLS];
  const int wave = threadIdx.x >> 6;
  const int lane = threadIdx.x & 63;

  const float4* sig4 = (const float4*)ws;   // sigma
  const float4 s0 = sig4[lane];
  const float4 s1 = sig4[lane + 64];

  float4 a0 = {0.f, 0.f, 0.f, 0.f};
  float4 a1 = {0.f, 0.f, 0.f, 0.f};

  const int gw = blockIdx.x * 4 + wave;
  const int nw = gridDim.x * 4;
  for (int row = gw; row < ROWS; row += nw) {
    const float4* rp = (const float4*)(Kmat + (size_t)row * COLS);
    float4 k0 = rp[lane];
    float4 k1 = rp[lane + 64];
    float p = k0.x * s0.x + k0.y * s0.y + k0.z * s0.z + k0.w * s0.w
            + k1.x * s1.x + k1.y * s1.y + k1.z * s1.z + k1.w * s1.w;
#pragma unroll
    for (int off = 32; off; off >>= 1) p += __shfl_xor(p, off, 64);
    const float inv = 1.0f / (p + EPS);
    if (WRITE_OUT) {
      // out = K * sigma / (r+eps)   (== Q*n since a*n == 1)
      float4* wp = (float4*)(out + (size_t)row * COLS);
      float4 o0, o1;
      o0.x = k0.x * s0.x * inv; o0.y = k0.y * s0.y * inv;
      o0.z = k0.z * s0.z * inv; o0.w = k0.w * s0.w * inv;
      o1.x = k1.x * s1.x * inv; o1.y = k1.y * s1.y * inv;
      o1.z = k1.z * s1.z * inv; o1.w = k1.w * s1.w * inv;
      wp[lane] = o0;
      wp[lane + 64] = o1;
    } else {
      a0.x += k0.x * inv; a0.y += k0.y * inv;
      a0.z += k0.z * inv; a0.w += k0.w * inv;
      a1.x += k1.x * inv; a1.y += k1.y * inv;
      a1.z += k1.z * inv; a1.w += k1.w * inv;
    }
  }

  if (!WRITE_OUT) {
    *(float4*)&lds[wave][4 * lane] = a0;
    *(float4*)&lds[wave][256 + 4 * lane] = a1;
    __syncthreads();
    float* tsum = ws + COLS;
    int j = threadIdx.x;
    float v = lds[0][j] + lds[1][j] + lds[2][j] + lds[3][j];
    atomicAdd(&tsum[j], v);
    j += 256;
    v = lds[0][j] + lds[1][j] + lds[2][j] + lds[3][j];
    atomicAdd(&tsum[j], v);
  }
}

// ---- sigma update: sigma = b / (sigma*a*tsum + eps); tsum = 0 ----
__global__ __launch_bounds__(512) void ipot_sigma_kernel(float* __restrict__ ws) {
  const int j = threadIdx.x;  // 512 threads, 1 block
  float* sigma = ws;
  float* tsum = ws + COLS;
  const float t = tsum[j];
  const float colsum = sigma[j] * A_M * t;
  sigma[j] = B_M / (colsum + EPS);
  tsum[j] = 0.0f;
}

extern "C" void kernel_launch(void* const* d_in, const int* in_sizes, int n_in,
                              void* d_out, int out_size, void* d_ws, size_t ws_size,
                              hipStream_t stream) {
  const float* C = (const float*)d_in[0];
  float* out = (float*)d_out;           // doubles as K_mat scratch
  float* ws = (float*)d_ws;             // sigma[512] + tsum[512]

  ipot_init_kernel<<<INIT_BLOCKS, 256, 0, stream>>>(C, out, ws);

  // 19 sigma updates (sigma_1 .. sigma_19)
  for (int t = 0; t < 19; ++t) {
    ipot_pass_kernel<false><<<PASS_BLOCKS, 256, 0, stream>>>(out, out, ws);
    ipot_sigma_kernel<<<1, 512, 0, stream>>>(ws);
  }
  // Final pass: Q_20 * n using sigma_19, written in place over K_mat.
  ipot_pass_kernel<true><<<PASS_BLOCKS, 256, 0, stream>>>(out, out, ws);
}